// Round 6
// baseline (963.634 us; speedup 1.0000x reference)
//
#include <hip/hip_runtime.h>

#define NN 200000
#define NE 800000
#define NG 4096
#define AD 128
#define HD 256
#define LN_EPS 1e-5f
#define NB 782   // ceil(NN/256)

typedef __attribute__((ext_vector_type(8))) short     bf16x8;
typedef __attribute__((ext_vector_type(8))) unsigned short us8;
typedef __attribute__((ext_vector_type(4))) unsigned short us4;
typedef __attribute__((ext_vector_type(4))) float     f32x4;

__device__ __forceinline__ float leaky(float v){ return v > 0.f ? v : 0.2f*v; }

__device__ __forceinline__ unsigned short f2bf(float f){
  unsigned u = __float_as_uint(f);
  return (unsigned short)((u + 0x7FFFu + ((u >> 16) & 1u)) >> 16);
}
__device__ __forceinline__ float bf2f(unsigned short h){ return __uint_as_float(((unsigned)h) << 16); }

__device__ __forceinline__ unsigned fkey(float f){
  unsigned u = __float_as_uint(f);
  return (u & 0x80000000u) ? ~u : (u | 0x80000000u);
}
__device__ __forceinline__ float fdec(unsigned k){
  return (k & 0x80000000u) ? __uint_as_float(k & 0x7FFFFFFFu) : __uint_as_float(~k);
}

// ---------------- CSR build ----------------
__global__ __launch_bounds__(256) void k_zero(int* __restrict__ cur){
  int i = blockIdx.x * 256 + threadIdx.x;
  if (i < NN) cur[i] = 0;
}

__global__ __launch_bounds__(256) void k_count(const int* __restrict__ ei, int* __restrict__ cur){
  int e = blockIdx.x * 256 + threadIdx.x;
  atomicAdd(&cur[ei[NE + e]], 1);
}

__global__ __launch_bounds__(256) void k_scanA(const int* __restrict__ cur, int* __restrict__ partial){
  __shared__ int sd[256];
  int t = threadIdx.x, b = blockIdx.x, i = b * 256 + t;
  sd[t] = (i < NN) ? cur[i] : 0;
  __syncthreads();
  for (int off = 128; off >= 1; off >>= 1){
    if (t < off) sd[t] += sd[t + off];
    __syncthreads();
  }
  if (t == 0) partial[b] = sd[0];
}

__global__ __launch_bounds__(1024) void k_scanB(const int* __restrict__ partial,
                                                int* __restrict__ scanoff, int* __restrict__ rowptr){
  __shared__ int sd[1024];
  int t = threadIdx.x;
  int v = (t < NB) ? partial[t] : 0;
  sd[t] = v; __syncthreads();
  for (int off = 1; off < 1024; off <<= 1){
    int u = (t >= off) ? sd[t - off] : 0;
    __syncthreads();
    sd[t] += u;
    __syncthreads();
  }
  if (t < NB) scanoff[t] = sd[t] - v;
  if (t == 0) rowptr[NN] = NE;
}

__global__ __launch_bounds__(256) void k_scanC(int* __restrict__ cur, const int* __restrict__ scanoff,
                                               int* __restrict__ rowptr){
  __shared__ int sd[256];
  int t = threadIdx.x, b = blockIdx.x, i = b * 256 + t;
  int v = (i < NN) ? cur[i] : 0;
  sd[t] = v; __syncthreads();
  for (int off = 1; off < 256; off <<= 1){
    int u = (t >= off) ? sd[t - off] : 0;
    __syncthreads();
    sd[t] += u;
    __syncthreads();
  }
  if (i < NN){ rowptr[i] = scanoff[b] + sd[t] - v; cur[i] = 0; }
}

__global__ __launch_bounds__(256) void k_fill(const int* __restrict__ ei,
                                              const int* __restrict__ rowptr,
                                              int* __restrict__ cur,
                                              int* __restrict__ col){
  int e = blockIdx.x * 256 + threadIdx.x;
  int s = ei[e], d = ei[NE + e];
  int pos = atomicAdd(&cur[d], 1);
  col[rowptr[d] + pos] = s;
}

__global__ __launch_bounds__(256) void k_initG(unsigned* __restrict__ Gk){
  int i = blockIdx.x * 256 + threadIdx.x;
  Gk[i] = 0x00800000u;                      // fkey(-FLT_MAX)
}

// weights: f32 [K][256] -> bf16 transposed [256][K]
__global__ __launch_bounds__(256) void k_wprep(const float* __restrict__ src,
                                               unsigned short* __restrict__ dst, int K){
  int k = blockIdx.x, n = threadIdx.x;
  dst[(size_t)n * K + k] = f2bf(src[(size_t)k * 256 + n]);
}

// ---------------- fused GIN layer 1: wave-per-row gather, MFMA MLP, LN+leaky -> bf16 H1 ----------------
__global__ __launch_bounds__(256) void k_layer1(const float* __restrict__ x,
                                                const int* __restrict__ rowptr,
                                                const int* __restrict__ col,
                                                const unsigned short* __restrict__ W1T,  // [256][128]
                                                const float* __restrict__ b1,
                                                const unsigned short* __restrict__ W2T,  // [256][256]
                                                const float* __restrict__ b2,
                                                const float* __restrict__ lng,
                                                const float* __restrict__ lnb,
                                                unsigned short* __restrict__ H1){
  __shared__ alignas(16) char sS[16 * 256 + 16 * 512];   // zS 4KB | tS 8KB
  __shared__ float2 redS[16][4];
  char* zS = sS;
  char* tS = sS + 4096;
  const int tid = threadIdx.x;
  const int l = tid & 63, wv = tid >> 6;
  const int cl = l & 15, kg = l >> 4;
  const int row0 = blockIdx.x * 16;

  // ---- gather: one wave per row (lane owns 2 f32 = 8B), 4 passes; col loaded coalesced + shfl ----
  const float2* x2 = (const float2*)x;
  #pragma unroll
  for (int pass = 0; pass < 4; ++pass){
    const int r = pass * 4 + wv;
    const int row = row0 + r;
    float2 s = x2[(size_t)row * 64 + l];
    float ax = s.x, ay = s.y;
    const int p = rowptr[row], pe = rowptr[row + 1];
    for (int base = p; base < pe; base += 64){
      const int nn = min(64, pe - base);
      int idx = col[base + (l < nn ? l : 0)];
      int q = 0;
      for (; q + 4 <= nn; q += 4){
        int j0 = __shfl(idx, q),     j1 = __shfl(idx, q + 1);
        int j2 = __shfl(idx, q + 2), j3 = __shfl(idx, q + 3);
        float2 b0 = x2[(size_t)j0 * 64 + l], b1v = x2[(size_t)j1 * 64 + l];
        float2 b2v = x2[(size_t)j2 * 64 + l], b3 = x2[(size_t)j3 * 64 + l];
        ax += (b0.x + b1v.x) + (b2v.x + b3.x);
        ay += (b0.y + b1v.y) + (b2v.y + b3.y);
      }
      for (; q < nn; ++q){
        int j = __shfl(idx, q);
        float2 b = x2[(size_t)j * 64 + l];
        ax += b.x; ay += b.y;
      }
    }
    unsigned pk = (unsigned)f2bf(ax) | ((unsigned)f2bf(ay) << 16);
    *(unsigned*)&zS[r * 256 + ((l * 4) ^ ((r & 7) << 4))] = pk;
  }
  __syncthreads();

  // ---- GEMM-A: t = relu(z @ w1 + b1), K=128; wave owns 64-col strip ----
  f32x4 acc[4];
  #pragma unroll
  for (int nt = 0; nt < 4; ++nt){
    float bv = b1[wv * 64 + nt * 16 + cl];
    acc[nt] = (f32x4){bv, bv, bv, bv};
  }
  #pragma unroll
  for (int ks = 0; ks < 4; ++ks){
    const int kb = (ks * 32 + kg * 8) * 2;
    bf16x8 a0 = *(const bf16x8*)&zS[cl * 256 + (kb ^ ((cl & 7) << 4))];
    #pragma unroll
    for (int nt = 0; nt < 4; ++nt){
      bf16x8 b = *(const bf16x8*)(W1T + (size_t)(wv * 64 + nt * 16 + cl) * AD + ks * 32 + kg * 8);
      acc[nt] = __builtin_amdgcn_mfma_f32_16x16x32_bf16(a0, b, acc[nt], 0, 0, 0);
    }
  }
  #pragma unroll
  for (int nt = 0; nt < 4; ++nt)
    #pragma unroll
    for (int rg = 0; rg < 4; ++rg){
      float v = fmaxf(acc[nt][rg], 0.f);
      int row = kg * 4 + rg;
      int cc = wv * 64 + nt * 16 + cl;
      *(unsigned short*)&tS[row * 512 + ((cc * 2) ^ ((row & 7) << 4))] = f2bf(v);
    }
  __syncthreads();

  // ---- GEMM-B: h = t @ w2 + b2, K=256 ----
  #pragma unroll
  for (int nt = 0; nt < 4; ++nt){
    float bv = b2[wv * 64 + nt * 16 + cl];
    acc[nt] = (f32x4){bv, bv, bv, bv};
  }
  #pragma unroll
  for (int ks = 0; ks < 8; ++ks){
    const int kb = (ks * 32 + kg * 8) * 2;
    bf16x8 a0 = *(const bf16x8*)&tS[cl * 512 + (kb ^ ((cl & 7) << 4))];
    #pragma unroll
    for (int nt = 0; nt < 4; ++nt){
      bf16x8 b = *(const bf16x8*)(W2T + (size_t)(wv * 64 + nt * 16 + cl) * HD + ks * 32 + kg * 8);
      acc[nt] = __builtin_amdgcn_mfma_f32_16x16x32_bf16(a0, b, acc[nt], 0, 0, 0);
    }
  }

  // ---- LN(256) + leaky + bf16 store; row's cols span 4 waves -> LDS reduce ----
  float s1v[4], s2v[4];
  #pragma unroll
  for (int rg = 0; rg < 4; ++rg){
    float a = acc[0][rg] + acc[1][rg] + acc[2][rg] + acc[3][rg];
    float b = acc[0][rg]*acc[0][rg] + acc[1][rg]*acc[1][rg]
            + acc[2][rg]*acc[2][rg] + acc[3][rg]*acc[3][rg];
    #pragma unroll
    for (int off = 1; off <= 8; off <<= 1){ a += __shfl_xor(a, off); b += __shfl_xor(b, off); }
    s1v[rg] = a; s2v[rg] = b;
  }
  if (cl == 0){
    #pragma unroll
    for (int rg = 0; rg < 4; ++rg)
      redS[kg * 4 + rg][wv] = make_float2(s1v[rg], s2v[rg]);
  }
  __syncthreads();
  #pragma unroll
  for (int rg = 0; rg < 4; ++rg){
    int row = kg * 4 + rg;
    float t1 = redS[row][0].x + redS[row][1].x + redS[row][2].x + redS[row][3].x;
    float t2 = redS[row][0].y + redS[row][1].y + redS[row][2].y + redS[row][3].y;
    float m  = t1 * (1.f / HD);
    float vr = t2 * (1.f / HD) - m * m;
    float rs = rsqrtf(vr + LN_EPS);
    #pragma unroll
    for (int nt = 0; nt < 4; ++nt){
      int cc = wv * 64 + nt * 16 + cl;
      float v = (acc[nt][rg] - m) * rs * lng[cc] + lnb[cc];
      H1[(size_t)(row0 + row) * HD + cc] = f2bf(leaky(v));
    }
  }
}

// ---------------- fused GIN layer 2: wave-per-row gather -> MLP -> leaky -> segmented max ----------------
__global__ __launch_bounds__(256) void k_layer2(const unsigned short* __restrict__ H1,
                                                const int* __restrict__ rowptr,
                                                const int* __restrict__ col,
                                                const int* __restrict__ batch,
                                                const unsigned short* __restrict__ W1T,  // [256][256]
                                                const float* __restrict__ b1,
                                                const unsigned short* __restrict__ W2T,  // [256][256]
                                                const float* __restrict__ b2,
                                                unsigned* __restrict__ Gk){
  __shared__ alignas(16) char sS[16 * 512 * 2];   // zS 8KB | tS 8KB ; later overlaid by stageF 16KB
  char* zS = sS;
  char* tS = sS + 8192;
  float* stageF = (float*)sS;
  const int tid = threadIdx.x;
  const int l = tid & 63, wv = tid >> 6;
  const int cl = l & 15, kg = l >> 4;
  const int row0 = blockIdx.x * 16;

  // ---- gather: one wave per row (lane owns 4 bf16 = 8B), 4 passes; col coalesced + shfl ----
  #pragma unroll
  for (int pass = 0; pass < 4; ++pass){
    const int r = pass * 4 + wv;
    const int row = row0 + r;
    us4 s = *(const us4*)(H1 + (size_t)row * HD + l * 4);
    float f0 = bf2f(s[0]), f1 = bf2f(s[1]), f2 = bf2f(s[2]), f3 = bf2f(s[3]);
    const int p = rowptr[row], pe = rowptr[row + 1];
    for (int base = p; base < pe; base += 64){
      const int nn = min(64, pe - base);
      int idx = col[base + (l < nn ? l : 0)];
      int q = 0;
      for (; q + 4 <= nn; q += 4){
        int j0 = __shfl(idx, q),     j1 = __shfl(idx, q + 1);
        int j2 = __shfl(idx, q + 2), j3 = __shfl(idx, q + 3);
        us4 b0 = *(const us4*)(H1 + (size_t)j0 * HD + l * 4);
        us4 b1v = *(const us4*)(H1 + (size_t)j1 * HD + l * 4);
        us4 b2v = *(const us4*)(H1 + (size_t)j2 * HD + l * 4);
        us4 b3 = *(const us4*)(H1 + (size_t)j3 * HD + l * 4);
        f0 += (bf2f(b0[0]) + bf2f(b1v[0])) + (bf2f(b2v[0]) + bf2f(b3[0]));
        f1 += (bf2f(b0[1]) + bf2f(b1v[1])) + (bf2f(b2v[1]) + bf2f(b3[1]));
        f2 += (bf2f(b0[2]) + bf2f(b1v[2])) + (bf2f(b2v[2]) + bf2f(b3[2]));
        f3 += (bf2f(b0[3]) + bf2f(b1v[3])) + (bf2f(b2v[3]) + bf2f(b3[3]));
      }
      for (; q < nn; ++q){
        int j = __shfl(idx, q);
        us4 b = *(const us4*)(H1 + (size_t)j * HD + l * 4);
        f0 += bf2f(b[0]); f1 += bf2f(b[1]); f2 += bf2f(b[2]); f3 += bf2f(b[3]);
      }
    }
    us4 o; o[0] = f2bf(f0); o[1] = f2bf(f1); o[2] = f2bf(f2); o[3] = f2bf(f3);
    *(us4*)&zS[r * 512 + ((l * 8) ^ ((r & 7) << 4))] = o;
  }
  __syncthreads();

  // ---- GEMM-A: t = relu(z @ w1 + b1), K=256 ----
  f32x4 acc[4];
  #pragma unroll
  for (int nt = 0; nt < 4; ++nt){
    float bv = b1[wv * 64 + nt * 16 + cl];
    acc[nt] = (f32x4){bv, bv, bv, bv};
  }
  #pragma unroll
  for (int ks = 0; ks < 8; ++ks){
    const int kb = (ks * 32 + kg * 8) * 2;
    bf16x8 a0 = *(const bf16x8*)&zS[cl * 512 + (kb ^ ((cl & 7) << 4))];
    #pragma unroll
    for (int nt = 0; nt < 4; ++nt){
      bf16x8 b = *(const bf16x8*)(W1T + (size_t)(wv * 64 + nt * 16 + cl) * HD + ks * 32 + kg * 8);
      acc[nt] = __builtin_amdgcn_mfma_f32_16x16x32_bf16(a0, b, acc[nt], 0, 0, 0);
    }
  }
  #pragma unroll
  for (int nt = 0; nt < 4; ++nt)
    #pragma unroll
    for (int rg = 0; rg < 4; ++rg){
      float v = fmaxf(acc[nt][rg], 0.f);
      int row = kg * 4 + rg;
      int cc = wv * 64 + nt * 16 + cl;
      *(unsigned short*)&tS[row * 512 + ((cc * 2) ^ ((row & 7) << 4))] = f2bf(v);
    }
  __syncthreads();

  // ---- GEMM-B: h = t @ w2 + b2, K=256 ----
  #pragma unroll
  for (int nt = 0; nt < 4; ++nt){
    float bv = b2[wv * 64 + nt * 16 + cl];
    acc[nt] = (f32x4){bv, bv, bv, bv};
  }
  #pragma unroll
  for (int ks = 0; ks < 8; ++ks){
    const int kb = (ks * 32 + kg * 8) * 2;
    bf16x8 a0 = *(const bf16x8*)&tS[cl * 512 + (kb ^ ((cl & 7) << 4))];
    #pragma unroll
    for (int nt = 0; nt < 4; ++nt){
      bf16x8 b = *(const bf16x8*)(W2T + (size_t)(wv * 64 + nt * 16 + cl) * HD + ks * 32 + kg * 8);
      acc[nt] = __builtin_amdgcn_mfma_f32_16x16x32_bf16(a0, b, acc[nt], 0, 0, 0);
    }
  }
  __syncthreads();   // all ds_reads of zS/tS done -> safe to overlay stageF

  // ---- stage leaky(h) as f32 in LDS ----
  #pragma unroll
  for (int nt = 0; nt < 4; ++nt)
    #pragma unroll
    for (int rg = 0; rg < 4; ++rg){
      int row = kg * 4 + rg;
      int cc = wv * 64 + nt * 16 + cl;
      stageF[row * HD + cc] = leaky(acc[nt][rg]);
    }
  __syncthreads();

  // ---- segmented max over sorted batch: one thread per column, ~2 atomics/col ----
  {
    const int c = tid;    // 0..255
    int gprev = batch[row0];
    float m = -3.4e38f;
    #pragma unroll
    for (int r = 0; r < 16; ++r){
      int g = batch[row0 + r];
      if (g != gprev){
        atomicMax(&Gk[(size_t)gprev * HD + c], fkey(m));
        m = -3.4e38f;
        gprev = g;
      }
      m = fmaxf(m, stageF[r * HD + c]);
    }
    atomicMax(&Gk[(size_t)gprev * HD + c], fkey(m));
  }
}

// ---------------- head: 8 graphs per block ----------------
__global__ __launch_bounds__(256) void head_kernel(const unsigned* __restrict__ Gk,
                                                   const float* __restrict__ w1,
                                                   const float* __restrict__ b1,
                                                   const float* __restrict__ lng,
                                                   const float* __restrict__ lnb,
                                                   const float* __restrict__ w2,
                                                   const float* __restrict__ b2,
                                                   float* __restrict__ out){
  __shared__ float gs[8][256];
  __shared__ float redA[8][4], redB[8][4];
  const int tid = threadIdx.x;
  const int g0 = blockIdx.x * 8;
  #pragma unroll
  for (int q = 0; q < 8; ++q) gs[q][tid] = fdec(Gk[(size_t)(g0 + q) * 256 + tid]);
  __syncthreads();

  float z[8][3];
  #pragma unroll
  for (int j = 0; j < 3; ++j){
    const int c = tid + j * 256;
    float a[8];
    float bv = b1[c];
    #pragma unroll
    for (int q = 0; q < 8; ++q) a[q] = bv;
    #pragma unroll 8
    for (int k = 0; k < 256; ++k){
      float w = w1[(size_t)k * 768 + c];
      #pragma unroll
      for (int q = 0; q < 8; ++q) a[q] += gs[q][k] * w;
    }
    #pragma unroll
    for (int q = 0; q < 8; ++q) z[q][j] = a[q];
  }

  const int lane = tid & 63, wv = tid >> 6;
  float mean[8], rs[8];
  {
    float s1[8], s2[8];
    #pragma unroll
    for (int q = 0; q < 8; ++q){
      s1[q] = z[q][0] + z[q][1] + z[q][2];
      s2[q] = z[q][0]*z[q][0] + z[q][1]*z[q][1] + z[q][2]*z[q][2];
    }
    #pragma unroll
    for (int off = 32; off >= 1; off >>= 1){
      #pragma unroll
      for (int q = 0; q < 8; ++q){ s1[q] += __shfl_xor(s1[q], off); s2[q] += __shfl_xor(s2[q], off); }
    }
    if (lane == 0){
      #pragma unroll
      for (int q = 0; q < 8; ++q){ redA[q][wv] = s1[q]; redB[q][wv] = s2[q]; }
    }
    __syncthreads();
    #pragma unroll
    for (int q = 0; q < 8; ++q){
      float t1 = redA[q][0] + redA[q][1] + redA[q][2] + redA[q][3];
      float t2 = redB[q][0] + redB[q][1] + redB[q][2] + redB[q][3];
      float m = t1 * (1.f / 768.f);
      float v = t2 * (1.f / 768.f) - m * m;
      mean[q] = m; rs[q] = rsqrtf(v + LN_EPS);
    }
  }
  __syncthreads();

  float p0[8], p1[8];
  #pragma unroll
  for (int q = 0; q < 8; ++q){ p0[q] = 0.f; p1[q] = 0.f; }
  #pragma unroll
  for (int j = 0; j < 3; ++j){
    const int c = tid + j * 256;
    float gcol = lng[c], bcol = lnb[c];
    float wa = w2[2 * c], wb = w2[2 * c + 1];
    #pragma unroll
    for (int q = 0; q < 8; ++q){
      float zz = leaky((z[q][j] - mean[q]) * rs[q] * gcol + bcol);
      p0[q] += zz * wa; p1[q] += zz * wb;
    }
  }
  #pragma unroll
  for (int off = 32; off >= 1; off >>= 1){
    #pragma unroll
    for (int q = 0; q < 8; ++q){ p0[q] += __shfl_xor(p0[q], off); p1[q] += __shfl_xor(p1[q], off); }
  }
  if (lane == 0){
    #pragma unroll
    for (int q = 0; q < 8; ++q){ redA[q][wv] = p0[q]; redB[q][wv] = p1[q]; }
  }
  __syncthreads();
  if (tid < 8){
    int q = tid;
    float l0 = redA[q][0] + redA[q][1] + redA[q][2] + redA[q][3] + b2[0];
    float l1 = redB[q][0] + redB[q][1] + redB[q][2] + redB[q][3] + b2[1];
    float mm = fmaxf(l0, l1);
    float e0 = expf(l0 - mm), e1 = expf(l1 - mm);
    float inv = 1.f / (e0 + e1);
    out[(size_t)(g0 + q) * 2 + 0] = e0 * inv;
    out[(size_t)(g0 + q) * 2 + 1] = e1 * inv;
  }
}

extern "C" void kernel_launch(void* const* d_in, const int* in_sizes, int n_in,
                              void* d_out, int out_size, void* d_ws, size_t ws_size,
                              hipStream_t stream){
  const float* x     = (const float*)d_in[0];
  const int*   ei    = (const int*)  d_in[1];
  const int*   batch = (const int*)  d_in[2];
  const float* g1w1  = (const float*)d_in[3];
  const float* g1b1  = (const float*)d_in[4];
  const float* g1w2  = (const float*)d_in[5];
  const float* g1b2  = (const float*)d_in[6];
  const float* g2w1  = (const float*)d_in[7];
  const float* g2b1  = (const float*)d_in[8];
  const float* g2w2  = (const float*)d_in[9];
  const float* g2b2  = (const float*)d_in[10];
  const float* lng   = (const float*)d_in[11];
  const float* lnb   = (const float*)d_in[12];
  const float* s2w1  = (const float*)d_in[13];
  const float* s2b1  = (const float*)d_in[14];
  const float* s2lng = (const float*)d_in[15];
  const float* s2lnb = (const float*)d_in[16];
  const float* s2w2  = (const float*)d_in[17];
  const float* s2b2  = (const float*)d_in[18];
  float* out = (float*)d_out;

  // workspace: 111,061,280 B total (proven safe)
  char* ws = (char*)d_ws;
  int*            rowptr  = (int*)(ws + 0);                    //   800,032 B
  int*            col     = (int*)(ws + 800032);               // 3,200,000 B
  unsigned*       Gk      = (unsigned*)(ws + 4000032);         // 4,194,304 B (aliases 'cur')
  int*            cur     = (int*)Gk;
  unsigned short* W1T1    = (unsigned short*)(ws + 8194336);   //    65,536 B
  unsigned short* W2T1    = (unsigned short*)(ws + 8259872);   //   131,072 B
  unsigned short* W1T2    = (unsigned short*)(ws + 8390944);   //   131,072 B
  unsigned short* W2T2    = (unsigned short*)(ws + 8522016);   //   131,072 B
  int*            partial = (int*)(ws + 8653088);              //     4,096 B
  int*            scanoff = (int*)(ws + 8657184);              //     4,096 B
  unsigned short* H1      = (unsigned short*)(ws + 8661280);   // 102,400,000 B

  k_zero <<<(NN + 255) / 256, 256, 0, stream>>>(cur);
  k_count<<<NE / 256,         256, 0, stream>>>(ei, cur);
  k_scanA<<<NB,               256, 0, stream>>>(cur, partial);
  k_scanB<<<1,               1024, 0, stream>>>(partial, scanoff, rowptr);
  k_scanC<<<NB,               256, 0, stream>>>(cur, scanoff, rowptr);
  k_fill <<<NE / 256,         256, 0, stream>>>(ei, rowptr, cur, col);
  k_initG<<<NG * HD / 256,    256, 0, stream>>>(Gk);
  k_wprep<<<128, 256, 0, stream>>>(g1w1, W1T1, 128);
  k_wprep<<<256, 256, 0, stream>>>(g1w2, W2T1, 256);
  k_wprep<<<256, 256, 0, stream>>>(g2w1, W1T2, 256);
  k_wprep<<<256, 256, 0, stream>>>(g2w2, W2T2, 256);
  k_layer1<<<NN / 16, 256, 0, stream>>>(x, rowptr, col, W1T1, g1b1, W2T1, g1b2, lng, lnb, H1);
  k_layer2<<<NN / 16, 256, 0, stream>>>(H1, rowptr, col, batch, W1T2, g2b1, W2T2, g2b2, Gk);
  head_kernel<<<NG / 8, 256, 0, stream>>>(Gk, s2w1, s2b1, s2lng, s2lnb, s2w2, s2b2, out);
}

// Round 7
// 941.091 us; speedup vs baseline: 1.0240x; 1.0240x over previous
//
#include <hip/hip_runtime.h>

#define NN 200000
#define NE 800000
#define NG 4096
#define AD 128
#define HD 256
#define LN_EPS 1e-5f
#define NB 782   // ceil(NN/256)

typedef __attribute__((ext_vector_type(8))) short     bf16x8;
typedef __attribute__((ext_vector_type(8))) unsigned short us8;
typedef __attribute__((ext_vector_type(4))) unsigned short us4;
typedef __attribute__((ext_vector_type(4))) float     f32x4;

__device__ __forceinline__ float leaky(float v){ return v > 0.f ? v : 0.2f*v; }

__device__ __forceinline__ unsigned short f2bf(float f){
  unsigned u = __float_as_uint(f);
  return (unsigned short)((u + 0x7FFFu + ((u >> 16) & 1u)) >> 16);
}
__device__ __forceinline__ float bf2f(unsigned short h){ return __uint_as_float(((unsigned)h) << 16); }

__device__ __forceinline__ unsigned fkey(float f){
  unsigned u = __float_as_uint(f);
  return (u & 0x80000000u) ? ~u : (u | 0x80000000u);
}
__device__ __forceinline__ float fdec(unsigned k){
  return (k & 0x80000000u) ? __uint_as_float(k & 0x7FFFFFFFu) : __uint_as_float(~k);
}

// ---------------- CSR build ----------------
__global__ __launch_bounds__(256) void k_zero(int* __restrict__ cur){
  int i = blockIdx.x * 256 + threadIdx.x;
  if (i < NN) cur[i] = 0;
}

__global__ __launch_bounds__(256) void k_count(const int* __restrict__ ei, int* __restrict__ cur){
  int e = blockIdx.x * 256 + threadIdx.x;
  atomicAdd(&cur[ei[NE + e]], 1);
}

__global__ __launch_bounds__(256) void k_scanA(const int* __restrict__ cur, int* __restrict__ partial){
  __shared__ int sd[256];
  int t = threadIdx.x, b = blockIdx.x, i = b * 256 + t;
  sd[t] = (i < NN) ? cur[i] : 0;
  __syncthreads();
  for (int off = 128; off >= 1; off >>= 1){
    if (t < off) sd[t] += sd[t + off];
    __syncthreads();
  }
  if (t == 0) partial[b] = sd[0];
}

__global__ __launch_bounds__(1024) void k_scanB(const int* __restrict__ partial,
                                                int* __restrict__ scanoff, int* __restrict__ rowptr){
  __shared__ int sd[1024];
  int t = threadIdx.x;
  int v = (t < NB) ? partial[t] : 0;
  sd[t] = v; __syncthreads();
  for (int off = 1; off < 1024; off <<= 1){
    int u = (t >= off) ? sd[t - off] : 0;
    __syncthreads();
    sd[t] += u;
    __syncthreads();
  }
  if (t < NB) scanoff[t] = sd[t] - v;
  if (t == 0) rowptr[NN] = NE;
}

__global__ __launch_bounds__(256) void k_scanC(int* __restrict__ cur, const int* __restrict__ scanoff,
                                               int* __restrict__ rowptr){
  __shared__ int sd[256];
  int t = threadIdx.x, b = blockIdx.x, i = b * 256 + t;
  int v = (i < NN) ? cur[i] : 0;
  sd[t] = v; __syncthreads();
  for (int off = 1; off < 256; off <<= 1){
    int u = (t >= off) ? sd[t - off] : 0;
    __syncthreads();
    sd[t] += u;
    __syncthreads();
  }
  if (i < NN){ rowptr[i] = scanoff[b] + sd[t] - v; cur[i] = 0; }
}

__global__ __launch_bounds__(256) void k_fill(const int* __restrict__ ei,
                                              const int* __restrict__ rowptr,
                                              int* __restrict__ cur,
                                              int* __restrict__ col){
  int e = blockIdx.x * 256 + threadIdx.x;
  int s = ei[e], d = ei[NE + e];
  int pos = atomicAdd(&cur[d], 1);
  col[rowptr[d] + pos] = s;
}

__global__ __launch_bounds__(256) void k_initG(unsigned* __restrict__ Gk){
  int i = blockIdx.x * 256 + threadIdx.x;
  Gk[i] = 0x00800000u;                      // fkey(-FLT_MAX)
}

// weights: f32 [K][256] -> bf16 transposed [256][K]
__global__ __launch_bounds__(256) void k_wprep(const float* __restrict__ src,
                                               unsigned short* __restrict__ dst, int K){
  int k = blockIdx.x, n = threadIdx.x;
  dst[(size_t)n * K + k] = f2bf(src[(size_t)k * 256 + n]);
}

// x f32 -> bf16 (streaming), 4 elems/thread
__global__ __launch_bounds__(256) void k_xprep(const float* __restrict__ x, unsigned short* __restrict__ X16){
  int i = blockIdx.x * 256 + threadIdx.x;   // 25,000 blocks: i < 6,400,000
  float4 v = ((const float4*)x)[i];
  us4 o; o[0] = f2bf(v.x); o[1] = f2bf(v.y); o[2] = f2bf(v.z); o[3] = f2bf(v.w);
  *(us4*)(X16 + (size_t)i * 4) = o;
}

// ---------------- fused GIN layer 1: 16 thr/row gather (f32 or bf16 x), MFMA MLP, LN+leaky -> bf16 H1 ----------------
template<int XBF>
__global__ __launch_bounds__(256) void k_layer1(const float* __restrict__ x,
                                                const unsigned short* __restrict__ X16,
                                                const int* __restrict__ rowptr,
                                                const int* __restrict__ col,
                                                const unsigned short* __restrict__ W1T,  // [256][128]
                                                const float* __restrict__ b1,
                                                const unsigned short* __restrict__ W2T,  // [256][256]
                                                const float* __restrict__ b2,
                                                const float* __restrict__ lng,
                                                const float* __restrict__ lnb,
                                                unsigned short* __restrict__ H1){
  __shared__ alignas(16) char sS[16 * 256 + 16 * 512];   // zS 4KB | tS 8KB
  __shared__ float2 redS[16][4];
  char* zS = sS;
  char* tS = sS + 4096;
  const int tid = threadIdx.x;
  const int l = tid & 63, wv = tid >> 6;
  const int cl = l & 15, kg = l >> 4;
  const int row0 = blockIdx.x * 16;

  { // ---- gather: row per 16-thread group, thread owns 8 cols (f32: 2x16B loads; bf16: 1x16B load) ----
    const int row = tid >> 4, sub = tid & 15;
    const int grow = row0 + row;
    float a[8];
    const int p = rowptr[grow], pe = rowptr[grow + 1];
    if constexpr (XBF){
      us8 s = *(const us8*)(X16 + (size_t)grow * AD + sub * 8);
      #pragma unroll
      for (int j = 0; j < 8; ++j) a[j] = bf2f(s[j]);
      int q = p;
      for (; q + 4 <= pe; q += 4){
        int j0 = col[q], j1 = col[q+1], j2 = col[q+2], j3 = col[q+3];
        us8 b0 = *(const us8*)(X16 + (size_t)j0 * AD + sub * 8);
        us8 b1v = *(const us8*)(X16 + (size_t)j1 * AD + sub * 8);
        us8 b2v = *(const us8*)(X16 + (size_t)j2 * AD + sub * 8);
        us8 b3 = *(const us8*)(X16 + (size_t)j3 * AD + sub * 8);
        #pragma unroll
        for (int j = 0; j < 8; ++j)
          a[j] += (bf2f(b0[j]) + bf2f(b1v[j])) + (bf2f(b2v[j]) + bf2f(b3[j]));
      }
      for (; q < pe; ++q){
        int jn = col[q];
        us8 b = *(const us8*)(X16 + (size_t)jn * AD + sub * 8);
        #pragma unroll
        for (int j = 0; j < 8; ++j) a[j] += bf2f(b[j]);
      }
    } else {
      const float4* x4 = (const float4*)x;
      float4 s0 = x4[(size_t)grow * 32 + sub * 2];
      float4 s1 = x4[(size_t)grow * 32 + sub * 2 + 1];
      a[0]=s0.x; a[1]=s0.y; a[2]=s0.z; a[3]=s0.w; a[4]=s1.x; a[5]=s1.y; a[6]=s1.z; a[7]=s1.w;
      int q = p;
      for (; q + 4 <= pe; q += 4){
        int j0 = col[q], j1 = col[q+1], j2 = col[q+2], j3 = col[q+3];
        float4 b00 = x4[(size_t)j0*32 + sub*2], b01 = x4[(size_t)j0*32 + sub*2 + 1];
        float4 b10 = x4[(size_t)j1*32 + sub*2], b11 = x4[(size_t)j1*32 + sub*2 + 1];
        float4 b20 = x4[(size_t)j2*32 + sub*2], b21 = x4[(size_t)j2*32 + sub*2 + 1];
        float4 b30 = x4[(size_t)j3*32 + sub*2], b31 = x4[(size_t)j3*32 + sub*2 + 1];
        a[0] += (b00.x + b10.x) + (b20.x + b30.x);
        a[1] += (b00.y + b10.y) + (b20.y + b30.y);
        a[2] += (b00.z + b10.z) + (b20.z + b30.z);
        a[3] += (b00.w + b10.w) + (b20.w + b30.w);
        a[4] += (b01.x + b11.x) + (b21.x + b31.x);
        a[5] += (b01.y + b11.y) + (b21.y + b31.y);
        a[6] += (b01.z + b11.z) + (b21.z + b31.z);
        a[7] += (b01.w + b11.w) + (b21.w + b31.w);
      }
      for (; q < pe; ++q){
        int j = col[q];
        float4 c0 = x4[(size_t)j*32 + sub*2], c1 = x4[(size_t)j*32 + sub*2 + 1];
        a[0]+=c0.x; a[1]+=c0.y; a[2]+=c0.z; a[3]+=c0.w;
        a[4]+=c1.x; a[5]+=c1.y; a[6]+=c1.z; a[7]+=c1.w;
      }
    }
    us8 o;
    #pragma unroll
    for (int j = 0; j < 8; ++j) o[j] = f2bf(a[j]);
    *(us8*)&zS[row * 256 + ((sub * 16) ^ ((row & 7) << 4))] = o;
  }
  __syncthreads();

  // ---- GEMM-A: t = relu(z @ w1 + b1), K=128; wave owns 64-col strip ----
  f32x4 acc[4];
  #pragma unroll
  for (int nt = 0; nt < 4; ++nt){
    float bv = b1[wv * 64 + nt * 16 + cl];
    acc[nt] = (f32x4){bv, bv, bv, bv};
  }
  #pragma unroll
  for (int ks = 0; ks < 4; ++ks){
    const int kb = (ks * 32 + kg * 8) * 2;
    bf16x8 a0 = *(const bf16x8*)&zS[cl * 256 + (kb ^ ((cl & 7) << 4))];
    #pragma unroll
    for (int nt = 0; nt < 4; ++nt){
      bf16x8 b = *(const bf16x8*)(W1T + (size_t)(wv * 64 + nt * 16 + cl) * AD + ks * 32 + kg * 8);
      acc[nt] = __builtin_amdgcn_mfma_f32_16x16x32_bf16(a0, b, acc[nt], 0, 0, 0);
    }
  }
  #pragma unroll
  for (int nt = 0; nt < 4; ++nt)
    #pragma unroll
    for (int rg = 0; rg < 4; ++rg){
      float v = fmaxf(acc[nt][rg], 0.f);
      int row = kg * 4 + rg;
      int cc = wv * 64 + nt * 16 + cl;
      *(unsigned short*)&tS[row * 512 + ((cc * 2) ^ ((row & 7) << 4))] = f2bf(v);
    }
  __syncthreads();

  // ---- GEMM-B: h = t @ w2 + b2, K=256 ----
  #pragma unroll
  for (int nt = 0; nt < 4; ++nt){
    float bv = b2[wv * 64 + nt * 16 + cl];
    acc[nt] = (f32x4){bv, bv, bv, bv};
  }
  #pragma unroll
  for (int ks = 0; ks < 8; ++ks){
    const int kb = (ks * 32 + kg * 8) * 2;
    bf16x8 a0 = *(const bf16x8*)&tS[cl * 512 + (kb ^ ((cl & 7) << 4))];
    #pragma unroll
    for (int nt = 0; nt < 4; ++nt){
      bf16x8 b = *(const bf16x8*)(W2T + (size_t)(wv * 64 + nt * 16 + cl) * HD + ks * 32 + kg * 8);
      acc[nt] = __builtin_amdgcn_mfma_f32_16x16x32_bf16(a0, b, acc[nt], 0, 0, 0);
    }
  }

  // ---- LN(256) + leaky + bf16 store; row's cols span 4 waves -> LDS reduce ----
  float s1v[4], s2v[4];
  #pragma unroll
  for (int rg = 0; rg < 4; ++rg){
    float a = acc[0][rg] + acc[1][rg] + acc[2][rg] + acc[3][rg];
    float b = acc[0][rg]*acc[0][rg] + acc[1][rg]*acc[1][rg]
            + acc[2][rg]*acc[2][rg] + acc[3][rg]*acc[3][rg];
    #pragma unroll
    for (int off = 1; off <= 8; off <<= 1){ a += __shfl_xor(a, off); b += __shfl_xor(b, off); }
    s1v[rg] = a; s2v[rg] = b;
  }
  if (cl == 0){
    #pragma unroll
    for (int rg = 0; rg < 4; ++rg)
      redS[kg * 4 + rg][wv] = make_float2(s1v[rg], s2v[rg]);
  }
  __syncthreads();
  #pragma unroll
  for (int rg = 0; rg < 4; ++rg){
    int row = kg * 4 + rg;
    float t1 = redS[row][0].x + redS[row][1].x + redS[row][2].x + redS[row][3].x;
    float t2 = redS[row][0].y + redS[row][1].y + redS[row][2].y + redS[row][3].y;
    float m  = t1 * (1.f / HD);
    float vr = t2 * (1.f / HD) - m * m;
    float rs = rsqrtf(vr + LN_EPS);
    #pragma unroll
    for (int nt = 0; nt < 4; ++nt){
      int cc = wv * 64 + nt * 16 + cl;
      float v = (acc[nt][rg] - m) * rs * lng[cc] + lnb[cc];
      H1[(size_t)(row0 + row) * HD + cc] = f2bf(leaky(v));
    }
  }
}

// ---------------- fused GIN layer 2: gather -> MLP -> leaky -> block-segmented max -> few atomics ----------------
__global__ __launch_bounds__(256) void k_layer2(const unsigned short* __restrict__ H1,
                                                const int* __restrict__ rowptr,
                                                const int* __restrict__ col,
                                                const int* __restrict__ batch,
                                                const unsigned short* __restrict__ W1T,  // [256][256]
                                                const float* __restrict__ b1,
                                                const unsigned short* __restrict__ W2T,  // [256][256]
                                                const float* __restrict__ b2,
                                                unsigned* __restrict__ Gk){
  __shared__ alignas(16) char sS[16 * 512 * 2];   // zS 8KB | tS 8KB ; later overlaid by stageF 16KB
  char* zS = sS;
  char* tS = sS + 8192;
  float* stageF = (float*)sS;
  const int tid = threadIdx.x;
  const int l = tid & 63, wv = tid >> 6;
  const int cl = l & 15, kg = l >> 4;
  const int row0 = blockIdx.x * 16;

  { // ---- gather: thread owns 16 bf16 cols of one row ----
    const int row = tid >> 4, sub = tid & 15;
    const int grow = row0 + row;
    us8 a0 = *(const us8*)(H1 + (size_t)grow * HD + sub * 16);
    us8 a1 = *(const us8*)(H1 + (size_t)grow * HD + sub * 16 + 8);
    float a[16];
    #pragma unroll
    for (int j = 0; j < 8; ++j){ a[j] = bf2f(a0[j]); a[8 + j] = bf2f(a1[j]); }
    const int p = rowptr[grow], pe = rowptr[grow + 1];
    int q = p;
    for (; q + 4 <= pe; q += 4){
      int j0 = col[q], j1 = col[q+1], j2 = col[q+2], j3 = col[q+3];
      us8 b00 = *(const us8*)(H1 + (size_t)j0*HD + sub*16), b01 = *(const us8*)(H1 + (size_t)j0*HD + sub*16 + 8);
      us8 b10 = *(const us8*)(H1 + (size_t)j1*HD + sub*16), b11 = *(const us8*)(H1 + (size_t)j1*HD + sub*16 + 8);
      us8 b20 = *(const us8*)(H1 + (size_t)j2*HD + sub*16), b21 = *(const us8*)(H1 + (size_t)j2*HD + sub*16 + 8);
      us8 b30 = *(const us8*)(H1 + (size_t)j3*HD + sub*16), b31 = *(const us8*)(H1 + (size_t)j3*HD + sub*16 + 8);
      #pragma unroll
      for (int j = 0; j < 8; ++j){
        a[j]     += (bf2f(b00[j]) + bf2f(b10[j])) + (bf2f(b20[j]) + bf2f(b30[j]));
        a[8 + j] += (bf2f(b01[j]) + bf2f(b11[j])) + (bf2f(b21[j]) + bf2f(b31[j]));
      }
    }
    for (; q < pe; ++q){
      int jn = col[q];
      us8 c0 = *(const us8*)(H1 + (size_t)jn*HD + sub*16), c1 = *(const us8*)(H1 + (size_t)jn*HD + sub*16 + 8);
      #pragma unroll
      for (int j = 0; j < 8; ++j){ a[j] += bf2f(c0[j]); a[8 + j] += bf2f(c1[j]); }
    }
    us8 o0, o1;
    #pragma unroll
    for (int j = 0; j < 8; ++j){ o0[j] = f2bf(a[j]); o1[j] = f2bf(a[8 + j]); }
    const int swz = (row & 7) << 4;
    *(us8*)&zS[row * 512 + ((sub * 32) ^ swz)]      = o0;
    *(us8*)&zS[row * 512 + ((sub * 32 + 16) ^ swz)] = o1;
  }
  __syncthreads();

  // ---- GEMM-A: t = relu(z @ w1 + b1), K=256 ----
  f32x4 acc[4];
  #pragma unroll
  for (int nt = 0; nt < 4; ++nt){
    float bv = b1[wv * 64 + nt * 16 + cl];
    acc[nt] = (f32x4){bv, bv, bv, bv};
  }
  #pragma unroll
  for (int ks = 0; ks < 8; ++ks){
    const int kb = (ks * 32 + kg * 8) * 2;
    bf16x8 a0 = *(const bf16x8*)&zS[cl * 512 + (kb ^ ((cl & 7) << 4))];
    #pragma unroll
    for (int nt = 0; nt < 4; ++nt){
      bf16x8 b = *(const bf16x8*)(W1T + (size_t)(wv * 64 + nt * 16 + cl) * HD + ks * 32 + kg * 8);
      acc[nt] = __builtin_amdgcn_mfma_f32_16x16x32_bf16(a0, b, acc[nt], 0, 0, 0);
    }
  }
  #pragma unroll
  for (int nt = 0; nt < 4; ++nt)
    #pragma unroll
    for (int rg = 0; rg < 4; ++rg){
      float v = fmaxf(acc[nt][rg], 0.f);
      int row = kg * 4 + rg;
      int cc = wv * 64 + nt * 16 + cl;
      *(unsigned short*)&tS[row * 512 + ((cc * 2) ^ ((row & 7) << 4))] = f2bf(v);
    }
  __syncthreads();

  // ---- GEMM-B: h = t @ w2 + b2, K=256 ----
  #pragma unroll
  for (int nt = 0; nt < 4; ++nt){
    float bv = b2[wv * 64 + nt * 16 + cl];
    acc[nt] = (f32x4){bv, bv, bv, bv};
  }
  #pragma unroll
  for (int ks = 0; ks < 8; ++ks){
    const int kb = (ks * 32 + kg * 8) * 2;
    bf16x8 a0 = *(const bf16x8*)&tS[cl * 512 + (kb ^ ((cl & 7) << 4))];
    #pragma unroll
    for (int nt = 0; nt < 4; ++nt){
      bf16x8 b = *(const bf16x8*)(W2T + (size_t)(wv * 64 + nt * 16 + cl) * HD + ks * 32 + kg * 8);
      acc[nt] = __builtin_amdgcn_mfma_f32_16x16x32_bf16(a0, b, acc[nt], 0, 0, 0);
    }
  }
  __syncthreads();   // all ds_reads of zS/tS done -> safe to overlay stageF

  // ---- stage leaky(h) as f32 in LDS ----
  #pragma unroll
  for (int nt = 0; nt < 4; ++nt)
    #pragma unroll
    for (int rg = 0; rg < 4; ++rg){
      int row = kg * 4 + rg;
      int cc = wv * 64 + nt * 16 + cl;
      stageF[row * HD + cc] = leaky(acc[nt][rg]);
    }
  __syncthreads();

  // ---- segmented max over sorted batch: one thread per column, ~2 atomics/col ----
  {
    const int c = tid;    // 0..255
    int gprev = batch[row0];
    float m = -3.4e38f;
    #pragma unroll
    for (int r = 0; r < 16; ++r){
      int g = batch[row0 + r];
      if (g != gprev){
        atomicMax(&Gk[(size_t)gprev * HD + c], fkey(m));
        m = -3.4e38f;
        gprev = g;
      }
      m = fmaxf(m, stageF[r * HD + c]);
    }
    atomicMax(&Gk[(size_t)gprev * HD + c], fkey(m));
  }
}

// ---------------- head: 8 graphs per block ----------------
__global__ __launch_bounds__(256) void head_kernel(const unsigned* __restrict__ Gk,
                                                   const float* __restrict__ w1,
                                                   const float* __restrict__ b1,
                                                   const float* __restrict__ lng,
                                                   const float* __restrict__ lnb,
                                                   const float* __restrict__ w2,
                                                   const float* __restrict__ b2,
                                                   float* __restrict__ out){
  __shared__ float gs[8][256];
  __shared__ float redA[8][4], redB[8][4];
  const int tid = threadIdx.x;
  const int g0 = blockIdx.x * 8;
  #pragma unroll
  for (int q = 0; q < 8; ++q) gs[q][tid] = fdec(Gk[(size_t)(g0 + q) * 256 + tid]);
  __syncthreads();

  float z[8][3];
  #pragma unroll
  for (int j = 0; j < 3; ++j){
    const int c = tid + j * 256;
    float a[8];
    float bv = b1[c];
    #pragma unroll
    for (int q = 0; q < 8; ++q) a[q] = bv;
    #pragma unroll 8
    for (int k = 0; k < 256; ++k){
      float w = w1[(size_t)k * 768 + c];
      #pragma unroll
      for (int q = 0; q < 8; ++q) a[q] += gs[q][k] * w;
    }
    #pragma unroll
    for (int q = 0; q < 8; ++q) z[q][j] = a[q];
  }

  const int lane = tid & 63, wv = tid >> 6;
  float mean[8], rs[8];
  {
    float s1[8], s2[8];
    #pragma unroll
    for (int q = 0; q < 8; ++q){
      s1[q] = z[q][0] + z[q][1] + z[q][2];
      s2[q] = z[q][0]*z[q][0] + z[q][1]*z[q][1] + z[q][2]*z[q][2];
    }
    #pragma unroll
    for (int off = 32; off >= 1; off >>= 1){
      #pragma unroll
      for (int q = 0; q < 8; ++q){ s1[q] += __shfl_xor(s1[q], off); s2[q] += __shfl_xor(s2[q], off); }
    }
    if (lane == 0){
      #pragma unroll
      for (int q = 0; q < 8; ++q){ redA[q][wv] = s1[q]; redB[q][wv] = s2[q]; }
    }
    __syncthreads();
    #pragma unroll
    for (int q = 0; q < 8; ++q){
      float t1 = redA[q][0] + redA[q][1] + redA[q][2] + redA[q][3];
      float t2 = redB[q][0] + redB[q][1] + redB[q][2] + redB[q][3];
      float m = t1 * (1.f / 768.f);
      float v = t2 * (1.f / 768.f) - m * m;
      mean[q] = m; rs[q] = rsqrtf(v + LN_EPS);
    }
  }
  __syncthreads();

  float p0[8], p1[8];
  #pragma unroll
  for (int q = 0; q < 8; ++q){ p0[q] = 0.f; p1[q] = 0.f; }
  #pragma unroll
  for (int j = 0; j < 3; ++j){
    const int c = tid + j * 256;
    float gcol = lng[c], bcol = lnb[c];
    float wa = w2[2 * c], wb = w2[2 * c + 1];
    #pragma unroll
    for (int q = 0; q < 8; ++q){
      float zz = leaky((z[q][j] - mean[q]) * rs[q] * gcol + bcol);
      p0[q] += zz * wa; p1[q] += zz * wb;
    }
  }
  #pragma unroll
  for (int off = 32; off >= 1; off >>= 1){
    #pragma unroll
    for (int q = 0; q < 8; ++q){ p0[q] += __shfl_xor(p0[q], off); p1[q] += __shfl_xor(p1[q], off); }
  }
  if (lane == 0){
    #pragma unroll
    for (int q = 0; q < 8; ++q){ redA[q][wv] = p0[q]; redB[q][wv] = p1[q]; }
  }
  __syncthreads();
  if (tid < 8){
    int q = tid;
    float l0 = redA[q][0] + redA[q][1] + redA[q][2] + redA[q][3] + b2[0];
    float l1 = redB[q][0] + redB[q][1] + redB[q][2] + redB[q][3] + b2[1];
    float mm = fmaxf(l0, l1);
    float e0 = expf(l0 - mm), e1 = expf(l1 - mm);
    float inv = 1.f / (e0 + e1);
    out[(size_t)(g0 + q) * 2 + 0] = e0 * inv;
    out[(size_t)(g0 + q) * 2 + 1] = e1 * inv;
  }
}

extern "C" void kernel_launch(void* const* d_in, const int* in_sizes, int n_in,
                              void* d_out, int out_size, void* d_ws, size_t ws_size,
                              hipStream_t stream){
  const float* x     = (const float*)d_in[0];
  const int*   ei    = (const int*)  d_in[1];
  const int*   batch = (const int*)  d_in[2];
  const float* g1w1  = (const float*)d_in[3];
  const float* g1b1  = (const float*)d_in[4];
  const float* g1w2  = (const float*)d_in[5];
  const float* g1b2  = (const float*)d_in[6];
  const float* g2w1  = (const float*)d_in[7];
  const float* g2b1  = (const float*)d_in[8];
  const float* g2w2  = (const float*)d_in[9];
  const float* g2b2  = (const float*)d_in[10];
  const float* lng   = (const float*)d_in[11];
  const float* lnb   = (const float*)d_in[12];
  const float* s2w1  = (const float*)d_in[13];
  const float* s2b1  = (const float*)d_in[14];
  const float* s2lng = (const float*)d_in[15];
  const float* s2lnb = (const float*)d_in[16];
  const float* s2w2  = (const float*)d_in[17];
  const float* s2b2  = (const float*)d_in[18];
  float* out = (float*)d_out;

  // base workspace: 111,061,280 B (proven safe); optional X16 beyond it
  char* ws = (char*)d_ws;
  int*            rowptr  = (int*)(ws + 0);                    //   800,032 B
  int*            col     = (int*)(ws + 800032);               // 3,200,000 B
  unsigned*       Gk      = (unsigned*)(ws + 4000032);         // 4,194,304 B (aliases 'cur')
  int*            cur     = (int*)Gk;
  unsigned short* W1T1    = (unsigned short*)(ws + 8194336);   //    65,536 B
  unsigned short* W2T1    = (unsigned short*)(ws + 8259872);   //   131,072 B
  unsigned short* W1T2    = (unsigned short*)(ws + 8390944);   //   131,072 B
  unsigned short* W2T2    = (unsigned short*)(ws + 8522016);   //   131,072 B
  int*            partial = (int*)(ws + 8653088);              //     4,096 B
  int*            scanoff = (int*)(ws + 8657184);              //     4,096 B
  unsigned short* H1      = (unsigned short*)(ws + 8661280);   // 102,400,000 B
  unsigned short* X16     = (unsigned short*)(ws + 111061280); //  51,200,000 B (optional)
  const bool bigws = (ws_size >= (size_t)111061280 + 51200000);

  k_zero <<<(NN + 255) / 256, 256, 0, stream>>>(cur);
  k_count<<<NE / 256,         256, 0, stream>>>(ei, cur);
  k_scanA<<<NB,               256, 0, stream>>>(cur, partial);
  k_scanB<<<1,               1024, 0, stream>>>(partial, scanoff, rowptr);
  k_scanC<<<NB,               256, 0, stream>>>(cur, scanoff, rowptr);
  k_fill <<<NE / 256,         256, 0, stream>>>(ei, rowptr, cur, col);
  k_initG<<<NG * HD / 256,    256, 0, stream>>>(Gk);
  k_wprep<<<128, 256, 0, stream>>>(g1w1, W1T1, 128);
  k_wprep<<<256, 256, 0, stream>>>(g1w2, W2T1, 256);
  k_wprep<<<256, 256, 0, stream>>>(g2w1, W1T2, 256);
  k_wprep<<<256, 256, 0, stream>>>(g2w2, W2T2, 256);
  if (bigws){
    k_xprep<<<25000, 256, 0, stream>>>(x, X16);
    k_layer1<1><<<NN / 16, 256, 0, stream>>>(x, X16, rowptr, col, W1T1, g1b1, W2T1, g1b2, lng, lnb, H1);
  } else {
    k_layer1<0><<<NN / 16, 256, 0, stream>>>(x, X16, rowptr, col, W1T1, g1b1, W2T1, g1b2, lng, lnb, H1);
  }
  k_layer2<<<NN / 16, 256, 0, stream>>>(H1, rowptr, col, batch, W1T2, g2b1, W2T2, g2b2, Gk);
  head_kernel<<<NG / 8, 256, 0, stream>>>(Gk, s2w1, s2b1, s2lng, s2lnb, s2w2, s2b2, out);
}

// Round 8
// 895.905 us; speedup vs baseline: 1.0756x; 1.0504x over previous
//
#include <hip/hip_runtime.h>

#define NN 200000
#define NE 800000
#define NG 4096
#define AD 128
#define HD 256
#define LN_EPS 1e-5f
#define NB 782   // ceil(NN/256)

typedef __attribute__((ext_vector_type(8))) short     bf16x8;
typedef __attribute__((ext_vector_type(8))) unsigned short us8;
typedef __attribute__((ext_vector_type(4))) unsigned short us4;
typedef __attribute__((ext_vector_type(4))) float     f32x4;

typedef __attribute__((address_space(1))) const unsigned gl_t;
typedef __attribute__((address_space(3))) unsigned       ld_t;

__device__ __forceinline__ float leaky(float v){ return v > 0.f ? v : 0.2f*v; }

__device__ __forceinline__ unsigned short f2bf(float f){
  unsigned u = __float_as_uint(f);
  return (unsigned short)((u + 0x7FFFu + ((u >> 16) & 1u)) >> 16);
}
__device__ __forceinline__ float bf2f(unsigned short h){ return __uint_as_float(((unsigned)h) << 16); }

__device__ __forceinline__ unsigned fkey(float f){
  unsigned u = __float_as_uint(f);
  return (u & 0x80000000u) ? ~u : (u | 0x80000000u);
}
__device__ __forceinline__ float fdec(unsigned k){
  return (k & 0x80000000u) ? __uint_as_float(k & 0x7FFFFFFFu) : __uint_as_float(~k);
}

// ---------------- CSR build ----------------
__global__ __launch_bounds__(256) void k_zero(int* __restrict__ cur){
  int i = blockIdx.x * 256 + threadIdx.x;
  if (i < NN) cur[i] = 0;
}

__global__ __launch_bounds__(256) void k_count(const int* __restrict__ ei, int* __restrict__ cur){
  int e = blockIdx.x * 256 + threadIdx.x;
  atomicAdd(&cur[ei[NE + e]], 1);
}

__global__ __launch_bounds__(256) void k_scanA(const int* __restrict__ cur, int* __restrict__ partial){
  __shared__ int sd[256];
  int t = threadIdx.x, b = blockIdx.x, i = b * 256 + t;
  sd[t] = (i < NN) ? cur[i] : 0;
  __syncthreads();
  for (int off = 128; off >= 1; off >>= 1){
    if (t < off) sd[t] += sd[t + off];
    __syncthreads();
  }
  if (t == 0) partial[b] = sd[0];
}

__global__ __launch_bounds__(1024) void k_scanB(const int* __restrict__ partial,
                                                int* __restrict__ scanoff, int* __restrict__ rowptr){
  __shared__ int sd[1024];
  int t = threadIdx.x;
  int v = (t < NB) ? partial[t] : 0;
  sd[t] = v; __syncthreads();
  for (int off = 1; off < 1024; off <<= 1){
    int u = (t >= off) ? sd[t - off] : 0;
    __syncthreads();
    sd[t] += u;
    __syncthreads();
  }
  if (t < NB) scanoff[t] = sd[t] - v;
  if (t == 0) rowptr[NN] = NE;
}

__global__ __launch_bounds__(256) void k_scanC(int* __restrict__ cur, const int* __restrict__ scanoff,
                                               int* __restrict__ rowptr){
  __shared__ int sd[256];
  int t = threadIdx.x, b = blockIdx.x, i = b * 256 + t;
  int v = (i < NN) ? cur[i] : 0;
  sd[t] = v; __syncthreads();
  for (int off = 1; off < 256; off <<= 1){
    int u = (t >= off) ? sd[t - off] : 0;
    __syncthreads();
    sd[t] += u;
    __syncthreads();
  }
  if (i < NN){ rowptr[i] = scanoff[b] + sd[t] - v; cur[i] = 0; }
}

__global__ __launch_bounds__(256) void k_fill(const int* __restrict__ ei,
                                              const int* __restrict__ rowptr,
                                              int* __restrict__ cur,
                                              int* __restrict__ col){
  int e = blockIdx.x * 256 + threadIdx.x;
  int s = ei[e], d = ei[NE + e];
  int pos = atomicAdd(&cur[d], 1);
  col[rowptr[d] + pos] = s;
}

__global__ __launch_bounds__(256) void k_initG(unsigned* __restrict__ Gk){
  int i = blockIdx.x * 256 + threadIdx.x;
  Gk[i] = 0x00800000u;                      // fkey(-FLT_MAX)
}

// weights: f32 [K][256] -> bf16 transposed [256][K]
__global__ __launch_bounds__(256) void k_wprep(const float* __restrict__ src,
                                               unsigned short* __restrict__ dst, int K){
  int k = blockIdx.x, n = threadIdx.x;
  dst[(size_t)n * K + k] = f2bf(src[(size_t)k * 256 + n]);
}

// ---------------- fused GIN layer 1: async-LDS gather (x f32, 512B rows), MFMA MLP, LN+leaky -> bf16 H1 ----------------
__global__ __launch_bounds__(256) void k_layer1(const float* __restrict__ x,
                                                const int* __restrict__ rowptr,
                                                const int* __restrict__ col,
                                                const unsigned short* __restrict__ W1T,  // [256][128]
                                                const float* __restrict__ b1,
                                                const unsigned short* __restrict__ W2T,  // [256][256]
                                                const float* __restrict__ b2,
                                                const float* __restrict__ lng,
                                                const float* __restrict__ lnb,
                                                unsigned short* __restrict__ H1){
  __shared__ alignas(16) char gbuf[32768 + 4096];  // [0,32K) gather slots (64x512B); zS at +32768 (4KB); tS aliases [0,8K)
  __shared__ float2 redS[16][4];
  char* zS = gbuf + 32768;
  char* tS = gbuf;
  const int tid = threadIdx.x;
  const int l = tid & 63, wv = tid >> 6;
  const int cl = l & 15, kg = l >> 4;
  const int row0 = blockIdx.x * 16;
  const int r16 = tid >> 4, sub = tid & 15;
  const int grow = row0 + r16;

  // ---- self row (f32, coalesced) ----
  const float4* x4 = (const float4*)x;
  float a[8];
  {
    float4 s0 = x4[(size_t)grow * 32 + sub * 2];
    float4 s1 = x4[(size_t)grow * 32 + sub * 2 + 1];
    a[0]=s0.x; a[1]=s0.y; a[2]=s0.z; a[3]=s0.w; a[4]=s1.x; a[5]=s1.y; a[6]=s1.z; a[7]=s1.w;
  }
  const int pr = rowptr[grow], per = rowptr[grow + 1];
  const int p0 = rowptr[row0], pend = rowptr[row0 + 16];

  // ---- chunked async gather: 64 neighbor rows (512B each) per chunk via global_load_lds ----
  for (int cs = p0; cs < pend; cs += 64){
    const int ns = min(64, pend - cs);
    {
      const int cidx = cs + wv * 16 + (l & 15);
      int colv = (cidx < pend) ? col[cidx] : 0;
      #pragma unroll
      for (int i = 0; i < 8; ++i){
        const int lslot = wv * 16 + i * 2 + (l >> 5);
        const int j = __shfl(colv, i * 2 + (l >> 5));
        if (lslot < ns){
          const void* src = (const void*)(x + (size_t)j * AD + (l & 31) * 4);
          void* dst = (void*)(gbuf + (wv * 16 + i * 2) * 512);
          __builtin_amdgcn_global_load_lds((gl_t*)src, (ld_t*)dst, 16, 0, 0);
        }
      }
    }
    __syncthreads();   // drains vmcnt -> all slots landed
    {
      const int qlo = max(pr, cs), qhi = min(per, cs + ns);
      for (int q = qlo; q < qhi; ++q){
        const float4* lrow = (const float4*)(gbuf + (q - cs) * 512 + sub * 32);
        float4 c0 = lrow[0], c1 = lrow[1];
        a[0]+=c0.x; a[1]+=c0.y; a[2]+=c0.z; a[3]+=c0.w;
        a[4]+=c1.x; a[5]+=c1.y; a[6]+=c1.z; a[7]+=c1.w;
      }
    }
    __syncthreads();   // slots free for next chunk
  }

  // ---- pack z -> zS (bf16, swizzled) ----
  {
    us8 o;
    #pragma unroll
    for (int j = 0; j < 8; ++j) o[j] = f2bf(a[j]);
    *(us8*)&zS[r16 * 256 + ((sub * 16) ^ ((r16 & 7) << 4))] = o;
  }
  __syncthreads();

  // ---- GEMM-A: t = relu(z @ w1 + b1), K=128; wave owns 64-col strip ----
  f32x4 acc[4];
  #pragma unroll
  for (int nt = 0; nt < 4; ++nt){
    float bv = b1[wv * 64 + nt * 16 + cl];
    acc[nt] = (f32x4){bv, bv, bv, bv};
  }
  #pragma unroll
  for (int ks = 0; ks < 4; ++ks){
    const int kb = (ks * 32 + kg * 8) * 2;
    bf16x8 a0 = *(const bf16x8*)&zS[cl * 256 + (kb ^ ((cl & 7) << 4))];
    #pragma unroll
    for (int nt = 0; nt < 4; ++nt){
      bf16x8 b = *(const bf16x8*)(W1T + (size_t)(wv * 64 + nt * 16 + cl) * AD + ks * 32 + kg * 8);
      acc[nt] = __builtin_amdgcn_mfma_f32_16x16x32_bf16(a0, b, acc[nt], 0, 0, 0);
    }
  }
  #pragma unroll
  for (int nt = 0; nt < 4; ++nt)
    #pragma unroll
    for (int rg = 0; rg < 4; ++rg){
      float v = fmaxf(acc[nt][rg], 0.f);
      int row = kg * 4 + rg;
      int cc = wv * 64 + nt * 16 + cl;
      *(unsigned short*)&tS[row * 512 + ((cc * 2) ^ ((row & 7) << 4))] = f2bf(v);
    }
  __syncthreads();

  // ---- GEMM-B: h = t @ w2 + b2, K=256 ----
  #pragma unroll
  for (int nt = 0; nt < 4; ++nt){
    float bv = b2[wv * 64 + nt * 16 + cl];
    acc[nt] = (f32x4){bv, bv, bv, bv};
  }
  #pragma unroll
  for (int ks = 0; ks < 8; ++ks){
    const int kb = (ks * 32 + kg * 8) * 2;
    bf16x8 a0 = *(const bf16x8*)&tS[cl * 512 + (kb ^ ((cl & 7) << 4))];
    #pragma unroll
    for (int nt = 0; nt < 4; ++nt){
      bf16x8 b = *(const bf16x8*)(W2T + (size_t)(wv * 64 + nt * 16 + cl) * HD + ks * 32 + kg * 8);
      acc[nt] = __builtin_amdgcn_mfma_f32_16x16x32_bf16(a0, b, acc[nt], 0, 0, 0);
    }
  }

  // ---- LN(256) + leaky + bf16 store; row's cols span 4 waves -> LDS reduce ----
  float s1v[4], s2v[4];
  #pragma unroll
  for (int rg = 0; rg < 4; ++rg){
    float aa = acc[0][rg] + acc[1][rg] + acc[2][rg] + acc[3][rg];
    float bb = acc[0][rg]*acc[0][rg] + acc[1][rg]*acc[1][rg]
             + acc[2][rg]*acc[2][rg] + acc[3][rg]*acc[3][rg];
    #pragma unroll
    for (int off = 1; off <= 8; off <<= 1){ aa += __shfl_xor(aa, off); bb += __shfl_xor(bb, off); }
    s1v[rg] = aa; s2v[rg] = bb;
  }
  if (cl == 0){
    #pragma unroll
    for (int rg = 0; rg < 4; ++rg)
      redS[kg * 4 + rg][wv] = make_float2(s1v[rg], s2v[rg]);
  }
  __syncthreads();
  #pragma unroll
  for (int rg = 0; rg < 4; ++rg){
    int row = kg * 4 + rg;
    float t1 = redS[row][0].x + redS[row][1].x + redS[row][2].x + redS[row][3].x;
    float t2 = redS[row][0].y + redS[row][1].y + redS[row][2].y + redS[row][3].y;
    float m  = t1 * (1.f / HD);
    float vr = t2 * (1.f / HD) - m * m;
    float rs = rsqrtf(vr + LN_EPS);
    #pragma unroll
    for (int nt = 0; nt < 4; ++nt){
      int cc = wv * 64 + nt * 16 + cl;
      float v = (acc[nt][rg] - m) * rs * lng[cc] + lnb[cc];
      H1[(size_t)(row0 + row) * HD + cc] = f2bf(leaky(v));
    }
  }
}

// ---------------- fused GIN layer 2: async-LDS gather (H1 bf16, 512B rows) -> MLP -> leaky -> segmented max ----------------
__global__ __launch_bounds__(256) void k_layer2(const unsigned short* __restrict__ H1,
                                                const int* __restrict__ rowptr,
                                                const int* __restrict__ col,
                                                const int* __restrict__ batch,
                                                const unsigned short* __restrict__ W1T,  // [256][256]
                                                const float* __restrict__ b1,
                                                const unsigned short* __restrict__ W2T,  // [256][256]
                                                const float* __restrict__ b2,
                                                unsigned* __restrict__ Gk){
  __shared__ alignas(16) char gbuf[32768 + 8192];  // [0,32K) gather; zS at +32768 (8KB); tS alias [0,8K); stageF alias [0,16K)
  char* zS = gbuf + 32768;
  char* tS = gbuf;
  float* stageF = (float*)gbuf;
  const int tid = threadIdx.x;
  const int l = tid & 63, wv = tid >> 6;
  const int cl = l & 15, kg = l >> 4;
  const int row0 = blockIdx.x * 16;
  const int r16 = tid >> 4, sub = tid & 15;
  const int grow = row0 + r16;

  // ---- self row (bf16, coalesced) ----
  float a[16];
  {
    us8 a0 = *(const us8*)(H1 + (size_t)grow * HD + sub * 16);
    us8 a1 = *(const us8*)(H1 + (size_t)grow * HD + sub * 16 + 8);
    #pragma unroll
    for (int j = 0; j < 8; ++j){ a[j] = bf2f(a0[j]); a[8 + j] = bf2f(a1[j]); }
  }
  const int pr = rowptr[grow], per = rowptr[grow + 1];
  const int p0 = rowptr[row0], pend = rowptr[row0 + 16];

  // ---- chunked async gather ----
  for (int cs = p0; cs < pend; cs += 64){
    const int ns = min(64, pend - cs);
    {
      const int cidx = cs + wv * 16 + (l & 15);
      int colv = (cidx < pend) ? col[cidx] : 0;
      #pragma unroll
      for (int i = 0; i < 8; ++i){
        const int lslot = wv * 16 + i * 2 + (l >> 5);
        const int j = __shfl(colv, i * 2 + (l >> 5));
        if (lslot < ns){
          const void* src = (const void*)(H1 + (size_t)j * HD + (l & 31) * 8);
          void* dst = (void*)(gbuf + (wv * 16 + i * 2) * 512);
          __builtin_amdgcn_global_load_lds((gl_t*)src, (ld_t*)dst, 16, 0, 0);
        }
      }
    }
    __syncthreads();
    {
      const int qlo = max(pr, cs), qhi = min(per, cs + ns);
      for (int q = qlo; q < qhi; ++q){
        const us8* lrow = (const us8*)(gbuf + (q - cs) * 512 + sub * 32);
        us8 c0 = lrow[0], c1 = lrow[1];
        #pragma unroll
        for (int j = 0; j < 8; ++j){ a[j] += bf2f(c0[j]); a[8 + j] += bf2f(c1[j]); }
      }
    }
    __syncthreads();
  }

  // ---- pack z -> zS (bf16, swizzled) ----
  {
    us8 o0, o1;
    #pragma unroll
    for (int j = 0; j < 8; ++j){ o0[j] = f2bf(a[j]); o1[j] = f2bf(a[8 + j]); }
    const int swz = (r16 & 7) << 4;
    *(us8*)&zS[r16 * 512 + ((sub * 32) ^ swz)]      = o0;
    *(us8*)&zS[r16 * 512 + ((sub * 32 + 16) ^ swz)] = o1;
  }
  __syncthreads();

  // ---- GEMM-A: t = relu(z @ w1 + b1), K=256 ----
  f32x4 acc[4];
  #pragma unroll
  for (int nt = 0; nt < 4; ++nt){
    float bv = b1[wv * 64 + nt * 16 + cl];
    acc[nt] = (f32x4){bv, bv, bv, bv};
  }
  #pragma unroll
  for (int ks = 0; ks < 8; ++ks){
    const int kb = (ks * 32 + kg * 8) * 2;
    bf16x8 a0 = *(const bf16x8*)&zS[cl * 512 + (kb ^ ((cl & 7) << 4))];
    #pragma unroll
    for (int nt = 0; nt < 4; ++nt){
      bf16x8 b = *(const bf16x8*)(W1T + (size_t)(wv * 64 + nt * 16 + cl) * HD + ks * 32 + kg * 8);
      acc[nt] = __builtin_amdgcn_mfma_f32_16x16x32_bf16(a0, b, acc[nt], 0, 0, 0);
    }
  }
  #pragma unroll
  for (int nt = 0; nt < 4; ++nt)
    #pragma unroll
    for (int rg = 0; rg < 4; ++rg){
      float v = fmaxf(acc[nt][rg], 0.f);
      int row = kg * 4 + rg;
      int cc = wv * 64 + nt * 16 + cl;
      *(unsigned short*)&tS[row * 512 + ((cc * 2) ^ ((row & 7) << 4))] = f2bf(v);
    }
  __syncthreads();

  // ---- GEMM-B: h = t @ w2 + b2, K=256 ----
  #pragma unroll
  for (int nt = 0; nt < 4; ++nt){
    float bv = b2[wv * 64 + nt * 16 + cl];
    acc[nt] = (f32x4){bv, bv, bv, bv};
  }
  #pragma unroll
  for (int ks = 0; ks < 8; ++ks){
    const int kb = (ks * 32 + kg * 8) * 2;
    bf16x8 a0 = *(const bf16x8*)&tS[cl * 512 + (kb ^ ((cl & 7) << 4))];
    #pragma unroll
    for (int nt = 0; nt < 4; ++nt){
      bf16x8 b = *(const bf16x8*)(W2T + (size_t)(wv * 64 + nt * 16 + cl) * HD + ks * 32 + kg * 8);
      acc[nt] = __builtin_amdgcn_mfma_f32_16x16x32_bf16(a0, b, acc[nt], 0, 0, 0);
    }
  }
  __syncthreads();   // all ds_reads of zS/tS done -> safe to overlay stageF

  // ---- stage leaky(h) as f32 in LDS ----
  #pragma unroll
  for (int nt = 0; nt < 4; ++nt)
    #pragma unroll
    for (int rg = 0; rg < 4; ++rg){
      int row = kg * 4 + rg;
      int cc = wv * 64 + nt * 16 + cl;
      stageF[row * HD + cc] = leaky(acc[nt][rg]);
    }
  __syncthreads();

  // ---- segmented max over sorted batch: one thread per column, ~2 atomics/col ----
  {
    const int c = tid;    // 0..255
    int gprev = batch[row0];
    float m = -3.4e38f;
    #pragma unroll
    for (int r = 0; r < 16; ++r){
      int g = batch[row0 + r];
      if (g != gprev){
        atomicMax(&Gk[(size_t)gprev * HD + c], fkey(m));
        m = -3.4e38f;
        gprev = g;
      }
      m = fmaxf(m, stageF[r * HD + c]);
    }
    atomicMax(&Gk[(size_t)gprev * HD + c], fkey(m));
  }
}

// ---------------- head: 8 graphs per block ----------------
__global__ __launch_bounds__(256) void head_kernel(const unsigned* __restrict__ Gk,
                                                   const float* __restrict__ w1,
                                                   const float* __restrict__ b1,
                                                   const float* __restrict__ lng,
                                                   const float* __restrict__ lnb,
                                                   const float* __restrict__ w2,
                                                   const float* __restrict__ b2,
                                                   float* __restrict__ out){
  __shared__ float gs[8][256];
  __shared__ float redA[8][4], redB[8][4];
  const int tid = threadIdx.x;
  const int g0 = blockIdx.x * 8;
  #pragma unroll
  for (int q = 0; q < 8; ++q) gs[q][tid] = fdec(Gk[(size_t)(g0 + q) * 256 + tid]);
  __syncthreads();

  float z[8][3];
  #pragma unroll
  for (int j = 0; j < 3; ++j){
    const int c = tid + j * 256;
    float a[8];
    float bv = b1[c];
    #pragma unroll
    for (int q = 0; q < 8; ++q) a[q] = bv;
    #pragma unroll 8
    for (int k = 0; k < 256; ++k){
      float w = w1[(size_t)k * 768 + c];
      #pragma unroll
      for (int q = 0; q < 8; ++q) a[q] += gs[q][k] * w;
    }
    #pragma unroll
    for (int q = 0; q < 8; ++q) z[q][j] = a[q];
  }

  const int lane = tid & 63, wv = tid >> 6;
  float mean[8], rs[8];
  {
    float s1[8], s2[8];
    #pragma unroll
    for (int q = 0; q < 8; ++q){
      s1[q] = z[q][0] + z[q][1] + z[q][2];
      s2[q] = z[q][0]*z[q][0] + z[q][1]*z[q][1] + z[q][2]*z[q][2];
    }
    #pragma unroll
    for (int off = 32; off >= 1; off >>= 1){
      #pragma unroll
      for (int q = 0; q < 8; ++q){ s1[q] += __shfl_xor(s1[q], off); s2[q] += __shfl_xor(s2[q], off); }
    }
    if (lane == 0){
      #pragma unroll
      for (int q = 0; q < 8; ++q){ redA[q][wv] = s1[q]; redB[q][wv] = s2[q]; }
    }
    __syncthreads();
    #pragma unroll
    for (int q = 0; q < 8; ++q){
      float t1 = redA[q][0] + redA[q][1] + redA[q][2] + redA[q][3];
      float t2 = redB[q][0] + redB[q][1] + redB[q][2] + redB[q][3];
      float m = t1 * (1.f / 768.f);
      float v = t2 * (1.f / 768.f) - m * m;
      mean[q] = m; rs[q] = rsqrtf(v + LN_EPS);
    }
  }
  __syncthreads();

  float p0[8], p1[8];
  #pragma unroll
  for (int q = 0; q < 8; ++q){ p0[q] = 0.f; p1[q] = 0.f; }
  #pragma unroll
  for (int j = 0; j < 3; ++j){
    const int c = tid + j * 256;
    float gcol = lng[c], bcol = lnb[c];
    float wa = w2[2 * c], wb = w2[2 * c + 1];
    #pragma unroll
    for (int q = 0; q < 8; ++q){
      float zz = leaky((z[q][j] - mean[q]) * rs[q] * gcol + bcol);
      p0[q] += zz * wa; p1[q] += zz * wb;
    }
  }
  #pragma unroll
  for (int off = 32; off >= 1; off >>= 1){
    #pragma unroll
    for (int q = 0; q < 8; ++q){ p0[q] += __shfl_xor(p0[q], off); p1[q] += __shfl_xor(p1[q], off); }
  }
  if (lane == 0){
    #pragma unroll
    for (int q = 0; q < 8; ++q){ redA[q][wv] = p0[q]; redB[q][wv] = p1[q]; }
  }
  __syncthreads();
  if (tid < 8){
    int q = tid;
    float l0 = redA[q][0] + redA[q][1] + redA[q][2] + redA[q][3] + b2[0];
    float l1 = redB[q][0] + redB[q][1] + redB[q][2] + redB[q][3] + b2[1];
    float mm = fmaxf(l0, l1);
    float e0 = expf(l0 - mm), e1 = expf(l1 - mm);
    float inv = 1.f / (e0 + e1);
    out[(size_t)(g0 + q) * 2 + 0] = e0 * inv;
    out[(size_t)(g0 + q) * 2 + 1] = e1 * inv;
  }
}

extern "C" void kernel_launch(void* const* d_in, const int* in_sizes, int n_in,
                              void* d_out, int out_size, void* d_ws, size_t ws_size,
                              hipStream_t stream){
  const float* x     = (const float*)d_in[0];
  const int*   ei    = (const int*)  d_in[1];
  const int*   batch = (const int*)  d_in[2];
  const float* g1w1  = (const float*)d_in[3];
  const float* g1b1  = (const float*)d_in[4];
  const float* g1w2  = (const float*)d_in[5];
  const float* g1b2  = (const float*)d_in[6];
  const float* g2w1  = (const float*)d_in[7];
  const float* g2b1  = (const float*)d_in[8];
  const float* g2w2  = (const float*)d_in[9];
  const float* g2b2  = (const float*)d_in[10];
  const float* lng   = (const float*)d_in[11];
  const float* lnb   = (const float*)d_in[12];
  const float* s2w1  = (const float*)d_in[13];
  const float* s2b1  = (const float*)d_in[14];
  const float* s2lng = (const float*)d_in[15];
  const float* s2lnb = (const float*)d_in[16];
  const float* s2w2  = (const float*)d_in[17];
  const float* s2b2  = (const float*)d_in[18];
  float* out = (float*)d_out;

  // workspace: 111,061,280 B total (proven safe)
  char* ws = (char*)d_ws;
  int*            rowptr  = (int*)(ws + 0);                    //   800,032 B
  int*            col     = (int*)(ws + 800032);               // 3,200,000 B
  unsigned*       Gk      = (unsigned*)(ws + 4000032);         // 4,194,304 B (aliases 'cur')
  int*            cur     = (int*)Gk;
  unsigned short* W1T1    = (unsigned short*)(ws + 8194336);   //    65,536 B
  unsigned short* W2T1    = (unsigned short*)(ws + 8259872);   //   131,072 B
  unsigned short* W1T2    = (unsigned short*)(ws + 8390944);   //   131,072 B
  unsigned short* W2T2    = (unsigned short*)(ws + 8522016);   //   131,072 B
  int*            partial = (int*)(ws + 8653088);              //     4,096 B
  int*            scanoff = (int*)(ws + 8657184);              //     4,096 B
  unsigned short* H1      = (unsigned short*)(ws + 8661280);   // 102,400,000 B

  k_zero <<<(NN + 255) / 256, 256, 0, stream>>>(cur);
  k_count<<<NE / 256,         256, 0, stream>>>(ei, cur);
  k_scanA<<<NB,               256, 0, stream>>>(cur, partial);
  k_scanB<<<1,               1024, 0, stream>>>(partial, scanoff, rowptr);
  k_scanC<<<NB,               256, 0, stream>>>(cur, scanoff, rowptr);
  k_fill <<<NE / 256,         256, 0, stream>>>(ei, rowptr, cur, col);
  k_initG<<<NG * HD / 256,    256, 0, stream>>>(Gk);
  k_wprep<<<128, 256, 0, stream>>>(g1w1, W1T1, 128);
  k_wprep<<<256, 256, 0, stream>>>(g1w2, W2T1, 256);
  k_wprep<<<256, 256, 0, stream>>>(g2w1, W1T2, 256);
  k_wprep<<<256, 256, 0, stream>>>(g2w2, W2T2, 256);
  k_layer1<<<NN / 16, 256, 0, stream>>>(x, rowptr, col, W1T1, g1b1, W2T1, g1b2, lng, lnb, H1);
  k_layer2<<<NN / 16, 256, 0, stream>>>(H1, rowptr, col, batch, W1T2, g2b1, W2T2, g2b2, Gk);
  head_kernel<<<NG / 8, 256, 0, stream>>>(Gk, s2w1, s2b1, s2lng, s2lnb, s2w2, s2b2, out);
}